// Round 1
// 297.071 us; speedup vs baseline: 1.1303x; 1.1303x over previous
//
#include <hip/hip_runtime.h>

// ---------------------------------------------------------------------------
// TimeSeriesGCN — bf16 MFMA pipeline, batch-as-M GEMMs on position-major slabs.
// prep_all:    block 0: edge_index -> dense bf16 Ahat[96][96]; rest: weights
// gcn_fused:   src -> h2 = relu(Ahat@(relu(Ahat@X@W1+b1)@W2)+b2) in ONE kernel
//              (replaces trans16 + agg_mm<16> + gcn12 + agg_mm<32>; saves
//               ~200MB of xt/xa/hw2 HBM round-trips)
// conv1/2/3:   pipelined hybrid GEMMs: A reg-prefetch + double-buffered LDS,
//              B direct-from-global fragswizzled (1 KB contiguous per wave)
// fc1_splitk:  c3 -> fp32 partials (6-way split-K, same pipeline)
// fc1_reduce:  partials -> feat (fp32 d_out) + fr (bf16 relu)
// cls1/cls2:   same template
// ---------------------------------------------------------------------------

typedef __attribute__((ext_vector_type(8))) short short8v;
typedef __attribute__((ext_vector_type(4))) float floatx4;

#define N_NODE 96
#define E_TOT  864
#define BATCH  8192ull

// ws layout, ushort elements
#define R0_OFF   0ull
#define R1_OFF   25165824ull
#define FR_OFF   50331648ull
#define R2_OFF   51380224ull
#define WT_OFF   52428800ull
#define W1N_OFF  (WT_OFF + 0)
#define W2N_OFF  (WT_OFF + 2048)
#define WC1_OFF  (WT_OFF + 4096)      // fragswizzled [4g][7ks][64][8]
#define WC2_OFF  (WT_OFF + 18432)     // [8g][10ks][64][8]
#define WC3_OFF  (WT_OFF + 59392)     // [16g][12ks][64][8]
#define WF1_OFF  (WT_OFF + 157696)    // [8g][96ks][64][8]
#define WL1_OFF  (WT_OFF + 550912)    // [8g][4ks][64][8]
#define WL2_OFF  (WT_OFF + 567296)    // [16g][4ks][64][8]
#define AH_OFF   (WT_OFF + 600064)    // dense Ahat bf16 [96][96]

__device__ __forceinline__ unsigned short f2b(float f) {
    unsigned int u = __builtin_bit_cast(unsigned int, f);
    u += 0x7fffu + ((u >> 16) & 1u);
    return (unsigned short)(u >> 16);
}
__device__ __forceinline__ float b2f(unsigned short h) {
    unsigned int u = ((unsigned int)h) << 16;
    return __builtin_bit_cast(float, u);
}

// ---------------------------------------------------------------------------
// Merged prep: block 0 builds dense Ahat from edges; blocks 1..2345 convert
// and fragswizzle all weights. Saves a launch and the whole-GPU-idle window
// of the single-block edges kernel.
// ---------------------------------------------------------------------------
__global__ void prep_all(const int* __restrict__ eidx,
                         const float* __restrict__ g1w, const float* __restrict__ g2w,
                         const float* __restrict__ w1, const float* __restrict__ w2,
                         const float* __restrict__ w3, const float* __restrict__ f1,
                         const float* __restrict__ l1, const float* __restrict__ l2,
                         unsigned short* __restrict__ wt,
                         unsigned short* __restrict__ adense) {
    __shared__ int rowv[E_TOT];
    __shared__ int colv[E_TOT];
    __shared__ int degi[N_NODE];
    __shared__ float dinv[N_NODE];
    __shared__ float ad[96 * 96];
    const int tid = threadIdx.x;
    if (blockIdx.x == 0) {
        for (int e = tid; e < E_TOT; e += 256) {
            int r, c;
            if (e < 768) { r = eidx[e]; c = eidx[768 + e]; }
            else         { r = e - 768; c = r; }
            rowv[e] = r; colv[e] = c;
        }
        for (int n = tid; n < N_NODE; n += 256) degi[n] = 0;
        for (int i = tid; i < 9216; i += 256) ad[i] = 0.f;
        __syncthreads();
        for (int e = tid; e < E_TOT; e += 256) atomicAdd(&degi[rowv[e]], 1);
        __syncthreads();
        for (int n = tid; n < N_NODE; n += 256)
            dinv[n] = rsqrtf(fmaxf((float)degi[n], 1e-12f));
        __syncthreads();
        for (int e = tid; e < E_TOT; e += 256)
            atomicAdd(&ad[rowv[e] * 96 + colv[e]], dinv[rowv[e]] * dinv[colv[e]]);
        __syncthreads();
        for (int i = tid; i < 9216; i += 256) adense[i] = f2b(ad[i]);
        return;
    }
    // weights path: fragswizzled B layout — group g (16 n-cols), kstep ks
    // (32 k), lane = quad*16 + n16, j in [0,8): elem = B[g*16+n16][ks*32+quad*8+j]
    long idx = (long)(blockIdx.x - 1) * 256 + tid;
    if (idx >= 600064) return;
    float v;
    if (idx < 2048) {                      // w1n[o][c] (unswizzled)
        int o = idx >> 5, c = idx & 31;
        v = (c < 16) ? g1w[c * 64 + o] : 0.f;
    } else if (idx < 4096) {               // w2n[g][c] (unswizzled)
        long j = idx - 2048; int g = j >> 6, c = j & 63;
        v = g2w[c * 32 + g];
    } else {
        long base, KS;
        int region;
        if      (idx < 18432)  { base = 4096;   KS = 7;  region = 0; }
        else if (idx < 59392)  { base = 18432;  KS = 10; region = 1; }
        else if (idx < 157696) { base = 59392;  KS = 12; region = 2; }
        else if (idx < 550912) { base = 157696; KS = 96; region = 3; }
        else if (idx < 567296) { base = 550912; KS = 4;  region = 4; }
        else                   { base = 567296; KS = 4;  region = 5; }
        long local = idx - base;
        long g  = local / (KS * 512);
        long rm = local % (KS * 512);
        long ks = rm / 512;
        int lane = (int)((rm % 512) / 8);
        int j    = (int)(rm % 8);
        int quad = lane >> 4, n16 = lane & 15;
        int n = (int)(g * 16 + n16);
        int k = (int)(ks * 32 + quad * 8 + j);
        switch (region) {
            case 0: { int t = k / 32,  c = k % 32;  v = w1[n * 224 + c * 7 + t]; } break;
            case 1: { int t = k / 64,  c = k % 64;  v = w2[n * 320 + c * 5 + t]; } break;
            case 2: { int t = k / 128, c = k % 128; v = w3[n * 384 + c * 3 + t]; } break;
            case 3: { int t = k / 256, o = k % 256; v = f1[(o * 12 + t) * 128 + n]; } break;
            case 4: v = l1[k * 128 + n]; break;
            default: v = (n < 210) ? l2[k * 210 + n] : 0.f; break;
        }
    }
    wt[idx] = f2b(v);
}

// ---------------------------------------------------------------------------
// Fused GCN front-end. One block = 4 batches, 256 threads (4 waves).
// LDS pool overlay (ushort offsets), 39936 ush = 79.9 KB -> 2 blocks/CU:
//   [0..12352)     FLT   src floats 4x1544          (S0/S1)
//   [0..9984)      AH2   Ahat [96][104]             (S2)
//   [0..13312)     HW2T  hw2^T [128 cols][104]      (S4->S5)
//   [13312..19968) Xt    X^T [64 cols][104]         (S1->S2)
//   [13312..23296) AH5   Ahat reload                (S5)
//   [19968..35328) XA    [384 rows][40] k-pad zero  (S2->S4)
//   [35328..39936) H1S   4 waves x [16][72]         (S3/S4 round-trip)
// W1^T/W2^T live entirely in per-lane B-fragments (registers).
// ---------------------------------------------------------------------------
__launch_bounds__(256)
__global__ void gcn_fused(const float* __restrict__ src,
                          const unsigned short* __restrict__ adense,
                          const unsigned short* __restrict__ w1n,
                          const unsigned short* __restrict__ w2n,
                          const float* __restrict__ b1,
                          const float* __restrict__ b2,
                          unsigned short* __restrict__ h2) {
    __shared__ __align__(16) unsigned short pool[39936];
    float* FLT = (float*)pool;
    unsigned short* AH2  = pool;
    unsigned short* HW2T = pool;
    unsigned short* Xt   = pool + 13312;
    unsigned short* AH5  = pool + 13312;
    unsigned short* XA   = pool + 19968;
    unsigned short* H1S  = pool + 35328;

    const int tid = threadIdx.x;
    const int w = tid >> 6, lane = tid & 63, quad = lane >> 4, m16 = lane & 15;
    const size_t b0 = (size_t)blockIdx.x * 4;

    // register preloads: W1/W2 B-fragments + biases (L2-hot, hidden under S0)
    short8v w1f[4], w2f[2][2];
    float bv1[4], bv2[2];
#pragma unroll
    for (int fn = 0; fn < 4; fn++) {
        w1f[fn] = *(const short8v*)&w1n[(fn * 16 + m16) * 32 + quad * 8];
        bv1[fn] = b1[fn * 16 + m16];
    }
#pragma unroll
    for (int fn = 0; fn < 2; fn++) {
#pragma unroll
        for (int kk = 0; kk < 2; kk++)
            w2f[fn][kk] = *(const short8v*)&w2n[(fn * 16 + m16) * 64 + kk * 32 + quad * 8];
        bv2[fn] = b2[fn * 16 + m16];
    }

    // S0: stage src floats; zero XA k-pad cols [16..32)
    for (int u = tid; u < 1536; u += 256) {
        int bl = u / 384, j = u % 384;
        *(float4*)&FLT[bl * 1544 + j * 4] = *(const float4*)&src[(b0 + bl) * 1536 + j * 4];
    }
    {
        short8v z = {0, 0, 0, 0, 0, 0, 0, 0};
        for (int u = tid; u < 768; u += 256)
            *(short8v*)&XA[(u >> 1) * 40 + 16 + (u & 1) * 8] = z;
    }
    __syncthreads();

    // S1: transpose FLT -> Xt[col=bl*16+c][node] (bf16, vectorized 16B writes)
    for (int u = tid; u < 768; u += 256) {
        int col = u / 12, seg = u % 12;
        int bl = col >> 4, c = col & 15;
        const float* f = &FLT[bl * 1544 + c * 96 + seg * 8];
        unsigned int d[4];
#pragma unroll
        for (int i = 0; i < 4; i++)
            d[i] = (unsigned int)f2b(f[2 * i]) | ((unsigned int)f2b(f[2 * i + 1]) << 16);
        *(uint4*)&Xt[col * 104 + seg * 8] = make_uint4(d[0], d[1], d[2], d[3]);
    }
    __syncthreads();

    // load Ahat (overwrites dead FLT)
    for (int u = tid; u < 1152; u += 256) {
        int r = u / 12, q = u % 12;
        *(short8v*)&AH2[r * 104 + q * 8] = *(const short8v*)&adense[r * 96 + q * 8];
    }
    __syncthreads();

    // S2: XA = Ahat @ X  (M=96, K=96, N=64; wave w -> cols w*16..w*16+16)
    {
        floatx4 acc[6] = {};
#pragma unroll
        for (int kk = 0; kk < 96; kk += 32) {
            short8v bfr = *(const short8v*)&Xt[(w * 16 + m16) * 104 + kk + quad * 8];
#pragma unroll
            for (int fm = 0; fm < 6; fm++) {
                short8v afr = *(const short8v*)&AH2[(fm * 16 + m16) * 104 + kk + quad * 8];
                acc[fm] = __builtin_amdgcn_mfma_f32_16x16x32_bf16(afr, bfr, acc[fm], 0, 0, 0);
            }
        }
        // store as GEMM-A rows: row384 = node*4 + bl (bl == w), k = c = m16
#pragma unroll
        for (int fm = 0; fm < 6; fm++)
#pragma unroll
            for (int r = 0; r < 4; r++) {
                int node = fm * 16 + quad * 4 + r;
                XA[(node * 4 + w) * 40 + m16] = f2b(acc[fm][r]);
            }
    }
    __syncthreads();

    // S3/S4: per wave, rows [w*96, w*96+96) in 6 chunks of 16.
    // gcn1: h1 = relu(XA@W1 + b1) -> wave-private LDS round-trip -> gcn2: h1@W2
    unsigned short* H1W = H1S + w * 1152;
    for (int cc = 0; cc < 6; cc++) {
        const int rowbase = w * 96 + cc * 16;
        short8v afr1 = *(const short8v*)&XA[(rowbase + m16) * 40 + quad * 8];
        floatx4 a1[4];
#pragma unroll
        for (int fn = 0; fn < 4; fn++) {
            floatx4 zc = {0.f, 0.f, 0.f, 0.f};
            a1[fn] = __builtin_amdgcn_mfma_f32_16x16x32_bf16(afr1, w1f[fn], zc, 0, 0, 0);
        }
#pragma unroll
        for (int fn = 0; fn < 4; fn++)
#pragma unroll
            for (int r = 0; r < 4; r++)
                H1W[(quad * 4 + r) * 72 + fn * 16 + m16] =
                    f2b(fmaxf(a1[fn][r] + bv1[fn], 0.f));
        // intra-wave ds_write -> ds_read: compiler inserts lgkmcnt, no barrier
        floatx4 a2[2] = {};
#pragma unroll
        for (int kk = 0; kk < 2; kk++) {
            short8v afr2 = *(const short8v*)&H1W[m16 * 72 + kk * 32 + quad * 8];
#pragma unroll
            for (int fn = 0; fn < 2; fn++)
                a2[fn] = __builtin_amdgcn_mfma_f32_16x16x32_bf16(afr2, w2f[fn][kk], a2[fn], 0, 0, 0);
        }
        // store transposed for S5 B-frags: HW2T[col=bl*32+ch][node]
#pragma unroll
        for (int fn = 0; fn < 2; fn++)
#pragma unroll
            for (int r = 0; r < 4; r++) {
                int row = rowbase + quad * 4 + r;
                int node = row >> 2, bl = row & 3;
                HW2T[(bl * 32 + fn * 16 + m16) * 104 + node] = f2b(a2[fn][r]);
            }
    }
    __syncthreads();

    // reload Ahat (Xt/XA-head dead)
    for (int u = tid; u < 1152; u += 256) {
        int r = u / 12, q = u % 12;
        *(short8v*)&AH5[r * 104 + q * 8] = *(const short8v*)&adense[r * 96 + q * 8];
    }
    __syncthreads();

    // S5: h2 = relu(Ahat @ hw2 + b2); wave w -> batch b0+w, 32 channels
    {
        floatx4 acc[6][2] = {};
#pragma unroll
        for (int kk = 0; kk < 96; kk += 32) {
            short8v bfr[2];
#pragma unroll
            for (int fn = 0; fn < 2; fn++)
                bfr[fn] = *(const short8v*)&HW2T[(w * 32 + fn * 16 + m16) * 104 + kk + quad * 8];
#pragma unroll
            for (int fm = 0; fm < 6; fm++) {
                short8v afr = *(const short8v*)&AH5[(fm * 16 + m16) * 104 + kk + quad * 8];
#pragma unroll
                for (int fn = 0; fn < 2; fn++)
                    acc[fm][fn] = __builtin_amdgcn_mfma_f32_16x16x32_bf16(afr, bfr[fn], acc[fm][fn], 0, 0, 0);
            }
        }
#pragma unroll
        for (int fm = 0; fm < 6; fm++)
#pragma unroll
            for (int fn = 0; fn < 2; fn++)
#pragma unroll
                for (int r = 0; r < 4; r++) {
                    int node = fm * 16 + quad * 4 + r;
                    h2[((size_t)node * BATCH + b0 + w) * 32 + fn * 16 + m16] =
                        f2b(fmaxf(acc[fm][fn][r] + bv2[fn], 0.f));
                }
    }
}

// ---------------------------------------------------------------------------
// Pipelined hybrid slab GEMM: per stage, barrier -> issue next A-tile global
// loads (regs) -> MFMA on LDS buf[p] (hides load latency) -> write regs ->
// buf[p^1]. One barrier/stage; out-of-range taps zero-fill (exact).
// B direct-from-global fragswizzled. BM=WM*32, BN=FN*32, waves 2x2.
// MODE 0: bf16 out + bias + relu. MODE 4: fp32 out [210-stride], masked.
// ---------------------------------------------------------------------------
template<int WM, int FN, int NTAP, int CIN, int NOUT, int STRIDE, int PAD, int LIN, int BK, int MODE>
__launch_bounds__(256)
__global__ void gemm_slab(const unsigned short* __restrict__ in,
                          const unsigned short* __restrict__ wn,
                          const float* __restrict__ bias,
                          unsigned short* __restrict__ outb,
                          float* __restrict__ outf) {
    constexpr int BM  = WM * 32;
    constexpr int BN  = FN * 32;
    constexpr int BKP = BK + 8;
    constexpr int CPT = CIN / BK;
    constexpr int NC  = NTAP * CPT;
    constexpr int KS  = NTAP * CIN / 32;     // fragswizzle ksteps
    constexpr int NV  = BM * BK / 8 / 256;   // vec8 loads per thread per tile
    constexpr int RPV = 256 / (BK / 8);      // rows per 256-thread sweep
    constexpr int SZ1 = 2 * BM * BKP;
    constexpr int SZ2 = (MODE == 4) ? 16 : BM * (BN + 8);
    constexpr int POOL = SZ1 > SZ2 ? SZ1 : SZ2;
    __shared__ __align__(16) unsigned short pool[POOL];
    const int tid = threadIdx.x;
    const size_t b0 = blockIdx.x * BM;
    const int n0 = blockIdx.y * BN;
    const int l  = blockIdx.z;
    const int w = tid >> 6, lane = tid & 63, quad = lane >> 4, m16 = lane & 15;
    const int wm = w >> 1, wq = w & 1;
    const int mbase = wm * (WM * 16), nbase = wq * (FN * 16);
    const int gw = (n0 + nbase) >> 4;        // first 16-col weight group
    const int lr = tid / (BK / 8);           // staging row
    const int lc = tid % (BK / 8);           // staging vec8 col
    floatx4 acc[WM][FN] = {};
    const short8v zz8 = {0, 0, 0, 0, 0, 0, 0, 0};

    short8v pre[NV], nxt[NV];
    // prologue: load + write tile 0
    {
        int pos = STRIDE * l - PAD;
        if (pos >= 0 && pos < LIN) {
            const unsigned short* ag = in + ((size_t)pos * BATCH + b0) * CIN;
#pragma unroll
            for (int v = 0; v < NV; v++)
                pre[v] = *(const short8v*)&ag[(size_t)(lr + v * RPV) * CIN + lc * 8];
        } else {
#pragma unroll
            for (int v = 0; v < NV; v++) pre[v] = zz8;
        }
#pragma unroll
        for (int v = 0; v < NV; v++)
            *(short8v*)&pool[(lr + v * RPV) * BKP + lc * 8] = pre[v];
    }
    int p = 0;
#pragma unroll
    for (int ch = 0; ch < NC; ++ch) {
        __syncthreads();                      // buf[p] ready; no VMEM in flight
        if (ch + 1 < NC) {                    // issue next tile's global loads
            int t = (ch + 1) / CPT, inner = (ch + 1) % CPT;
            int pos = STRIDE * l + t - PAD;
            if (pos >= 0 && pos < LIN) {
                const unsigned short* ag = in + ((size_t)pos * BATCH + b0) * CIN + inner * BK;
#pragma unroll
                for (int v = 0; v < NV; v++)
                    nxt[v] = *(const short8v*)&ag[(size_t)(lr + v * RPV) * CIN + lc * 8];
            } else {
#pragma unroll
                for (int v = 0; v < NV; v++) nxt[v] = zz8;
            }
        }
        // MFMA on buf[p] — overlaps with the loads above
        const unsigned short* As = pool + p * BM * BKP;
        const int kbase = (ch / CPT) * CIN + (ch % CPT) * BK;
#pragma unroll
        for (int kk = 0; kk < BK; kk += 32) {
            const int ksG = (kbase + kk) >> 5;
            short8v bfr[FN];
#pragma unroll
            for (int fn = 0; fn < FN; fn++)
                bfr[fn] = *(const short8v*)&wn[(((size_t)(gw + fn) * KS + ksG) << 9) + lane * 8];
#pragma unroll
            for (int fm = 0; fm < WM; fm++) {
                short8v afr = *(const short8v*)&As[(mbase + fm * 16 + m16) * BKP + kk + quad * 8];
#pragma unroll
                for (int fn = 0; fn < FN; fn++)
                    acc[fm][fn] = __builtin_amdgcn_mfma_f32_16x16x32_bf16(afr, bfr[fn], acc[fm][fn], 0, 0, 0);
            }
        }
        if (ch + 1 < NC) {                    // write next into other buffer
            unsigned short* Ad = pool + (p ^ 1) * BM * BKP;
#pragma unroll
            for (int v = 0; v < NV; v++)
                *(short8v*)&Ad[(lr + v * RPV) * BKP + lc * 8] = nxt[v];
        }
        p ^= 1;
    }

    if constexpr (MODE == 4) {
#pragma unroll
        for (int fn = 0; fn < FN; fn++) {
            int cg = n0 + nbase + fn * 16 + m16;
            float bv = (cg < 210) ? bias[cg] : 0.f;
            if (cg < 210) {
#pragma unroll
                for (int fm = 0; fm < WM; fm++)
#pragma unroll
                    for (int r = 0; r < 4; r++) {
                        size_t row = b0 + mbase + fm * 16 + quad * 4 + r;
                        outf[row * 210 + cg] = acc[fm][fn][r] + bv;
                    }
            }
        }
    } else {
        float bv[FN];
#pragma unroll
        for (int fn = 0; fn < FN; fn++) bv[fn] = bias[n0 + nbase + fn * 16 + m16];
        __syncthreads();                      // all MFMA reads of pool done
        unsigned short* Cs = pool;
#pragma unroll
        for (int fm = 0; fm < WM; fm++)
#pragma unroll
            for (int r = 0; r < 4; r++) {
                int row = mbase + fm * 16 + quad * 4 + r;
#pragma unroll
                for (int fn = 0; fn < FN; fn++)
                    Cs[row * (BN + 8) + nbase + fn * 16 + m16] =
                        f2b(fmaxf(acc[fm][fn][r] + bv[fn], 0.f));
            }
        __syncthreads();
        for (int u = tid; u < BM * (BN / 8); u += 256) {
            int r = u / (BN / 8), cc = u % (BN / 8);
            *(short8v*)&outb[((size_t)l * BATCH + b0 + r) * NOUT + n0 + cc * 8] =
                *(short8v*)&Cs[r * (BN + 8) + cc * 8];
        }
    }
}

// ---------------------------------------------------------------------------
// fc1 split-K, pipelined: A (c3) reg-prefetch + dbuf LDS; B fragswizzled.
// grid (64, 1, 6); z handles taps {2z, 2z+1} (K=512, 8 stages of 64).
// ---------------------------------------------------------------------------
__launch_bounds__(256)
__global__ void fc1_splitk(const unsigned short* __restrict__ c3,
                           const unsigned short* __restrict__ wf1,
                           float* __restrict__ part) {
    __shared__ __align__(16) unsigned short pool[2 * 128 * 72];
    const int tid = threadIdx.x;
    const size_t b0 = blockIdx.x * 128;
    const int kg = blockIdx.z;
    const int w = tid >> 6, lane = tid & 63, quad = lane >> 4, m16 = lane & 15;
    const int wm = w >> 1, wq = w & 1;
    const int mbase = wm * 64, nbase = wq * 64;
    const int gw = nbase >> 4;
    const int lr = tid >> 3, lc = tid & 7;
    floatx4 acc[4][4] = {};
    short8v pre[4], nxt[4];

    // stage s: t = kg*2 + (s>>2), inner = s&3
    {
        const unsigned short* ag = c3 + ((size_t)(kg * 2) * BATCH + b0) * 256;
#pragma unroll
        for (int v = 0; v < 4; v++)
            pre[v] = *(const short8v*)&ag[(size_t)(lr + v * 32) * 256 + lc * 8];
#pragma unroll
        for (int v = 0; v < 4; v++)
            *(short8v*)&pool[(lr + v * 32) * 72 + lc * 8] = pre[v];
    }
    int p = 0;
#pragma unroll
    for (int s = 0; s < 8; ++s) {
        __syncthreads();
        if (s + 1 < 8) {
            int t = kg * 2 + ((s + 1) >> 2), inner = (s + 1) & 3;
            const unsigned short* ag = c3 + ((size_t)t * BATCH + b0) * 256 + inner * 64;
#pragma unroll
            for (int v = 0; v < 4; v++)
                nxt[v] = *(const short8v*)&ag[(size_t)(lr + v * 32) * 256 + lc * 8];
        }
        const unsigned short* As = pool + p * 128 * 72;
        const int kbase = (kg * 2 + (s >> 2)) * 256 + (s & 3) * 64;
#pragma unroll
        for (int kk = 0; kk < 64; kk += 32) {
            const int ksG = (kbase + kk) >> 5;    // KS = 96
            short8v bfr[4];
#pragma unroll
            for (int fn = 0; fn < 4; fn++)
                bfr[fn] = *(const short8v*)&wf1[(((size_t)(gw + fn) * 96 + ksG) << 9) + lane * 8];
#pragma unroll
            for (int fm = 0; fm < 4; fm++) {
                short8v afr = *(const short8v*)&As[(mbase + fm * 16 + m16) * 72 + kk + quad * 8];
#pragma unroll
                for (int fn = 0; fn < 4; fn++)
                    acc[fm][fn] = __builtin_amdgcn_mfma_f32_16x16x32_bf16(afr, bfr[fn], acc[fm][fn], 0, 0, 0);
            }
        }
        if (s + 1 < 8) {
            unsigned short* Ad = pool + (p ^ 1) * 128 * 72;
#pragma unroll
            for (int v = 0; v < 4; v++)
                *(short8v*)&Ad[(lr + v * 32) * 72 + lc * 8] = nxt[v];
        }
        p ^= 1;
    }
    float* pg = part + (size_t)kg * BATCH * 128;
#pragma unroll
    for (int fm = 0; fm < 4; fm++)
#pragma unroll
        for (int r = 0; r < 4; r++) {
            size_t row = b0 + mbase + fm * 16 + quad * 4 + r;
#pragma unroll
            for (int fn = 0; fn < 4; fn++)
                pg[row * 128 + nbase + fn * 16 + m16] = acc[fm][fn][r];
        }
}

// ---------------------------------------------------------------------------
__launch_bounds__(256)
__global__ void fc1_reduce(const float* __restrict__ part, const float* __restrict__ bias,
                           float* __restrict__ feat, unsigned short* __restrict__ fr) {
    const size_t idx = (size_t)blockIdx.x * 256 + threadIdx.x;
    const size_t row = idx >> 5;
    const int    c4  = (int)(idx & 31);
    float4 s = *(const float4*)&bias[c4 * 4];
#pragma unroll
    for (int z = 0; z < 6; z++) {
        float4 p = *(const float4*)&part[(z * BATCH + row) * 128 + c4 * 4];
        s.x += p.x; s.y += p.y; s.z += p.z; s.w += p.w;
    }
    *(float4*)&feat[row * 128 + c4 * 4] = s;
    unsigned int d0 = (unsigned int)f2b(fmaxf(s.x, 0.f)) |
                      ((unsigned int)f2b(fmaxf(s.y, 0.f)) << 16);
    unsigned int d1 = (unsigned int)f2b(fmaxf(s.z, 0.f)) |
                      ((unsigned int)f2b(fmaxf(s.w, 0.f)) << 16);
    *(uint2*)&fr[row * 128 + c4 * 4] = make_uint2(d0, d1);
}

// ---------------------------------------------------------------------------
extern "C" void kernel_launch(void* const* d_in, const int* in_sizes, int n_in,
                              void* d_out, int out_size, void* d_ws, size_t ws_size,
                              hipStream_t stream) {
    const float* src  = (const float*)d_in[0];
    const int*   eidx = (const int*)  d_in[1];
    const float* g1w  = (const float*)d_in[2];
    const float* g1b  = (const float*)d_in[3];
    const float* g2w  = (const float*)d_in[4];
    const float* g2b  = (const float*)d_in[5];
    const float* cv1w = (const float*)d_in[6];
    const float* cv1b = (const float*)d_in[7];
    const float* cv2w = (const float*)d_in[8];
    const float* cv2b = (const float*)d_in[9];
    const float* cv3w = (const float*)d_in[10];
    const float* cv3b = (const float*)d_in[11];
    const float* fc1w = (const float*)d_in[12];
    const float* fc1b = (const float*)d_in[13];
    const float* cl1w = (const float*)d_in[14];
    const float* cl1b = (const float*)d_in[15];
    const float* cl2w = (const float*)d_in[16];
    const float* cl2b = (const float*)d_in[17];

    unsigned short* ws16 = (unsigned short*)d_ws;
    float* wsF = (float*)d_ws;
    float* out = (float*)d_out;

    unsigned short* h2  = ws16 + R0_OFF;
    unsigned short* c1  = ws16 + R1_OFF;
    unsigned short* c2  = ws16 + R0_OFF;
    unsigned short* c3  = ws16 + R1_OFF;
    float*          part = wsF;              // aliases dead c2 (R0)
    unsigned short* fr  = ws16 + FR_OFF;
    unsigned short* r2  = ws16 + R2_OFF;
    unsigned short* w1n = ws16 + W1N_OFF;
    unsigned short* w2n = ws16 + W2N_OFF;
    unsigned short* wc1 = ws16 + WC1_OFF;
    unsigned short* wc2 = ws16 + WC2_OFF;
    unsigned short* wc3 = ws16 + WC3_OFF;
    unsigned short* wf1 = ws16 + WF1_OFF;
    unsigned short* wl1 = ws16 + WL1_OFF;
    unsigned short* wl2 = ws16 + WL2_OFF;
    unsigned short* ah  = ws16 + AH_OFF;

    float* feat_out = out + 8192ull * 210ull;

    prep_all<<<2346, 256, 0, stream>>>(eidx, g1w, g2w, cv1w, cv2w, cv3w, fc1w, cl1w, cl2w,
                                       ws16 + WT_OFF, ah);
    gcn_fused<<<2048, 256, 0, stream>>>(src, ah, w1n, w2n, g1b, g2b, h2);
    // conv1: BM=256, BN=64, BK=32, 7 pipelined stages
    gemm_slab<8, 2, 7, 32, 64, 2, 3, 96, 32, 0>
        <<<dim3(32, 1, 48), 256, 0, stream>>>(h2, wc1, cv1b, c1, nullptr);
    // conv2: BM=128, BN=128, BK=64, 10 stages
    gemm_slab<4, 4, 5, 64, 128, 2, 2, 48, 64, 0>
        <<<dim3(64, 1, 24), 256, 0, stream>>>(c1, wc2, cv2b, c2, nullptr);
    // conv3: BM=128, BN=128 (y=2), BK=64, 6 stages
    gemm_slab<4, 4, 3, 128, 256, 2, 1, 24, 64, 0>
        <<<dim3(64, 2, 12), 256, 0, stream>>>(c2, wc3, cv3b, c3, nullptr);
    fc1_splitk<<<dim3(64, 1, 6), 256, 0, stream>>>(c3, wf1, part);
    fc1_reduce<<<1024, 256, 0, stream>>>(part, fc1b, feat_out, fr);
    gemm_slab<2, 2, 1, 128, 128, 1, 0, 1, 64, 0>
        <<<dim3(128, 2, 1), 256, 0, stream>>>(fr, wl1, cl1b, r2, nullptr);
    gemm_slab<2, 2, 1, 128, 256, 1, 0, 1, 64, 4>
        <<<dim3(128, 4, 1), 256, 0, stream>>>(r2, wl2, cl2b, nullptr, out);
}

// Round 2
// 274.487 us; speedup vs baseline: 1.2232x; 1.0823x over previous
//
#include <hip/hip_runtime.h>

// ---------------------------------------------------------------------------
// TimeSeriesGCN — bf16 MFMA pipeline, batch-as-M GEMMs on position-major slabs.
// prep_all:    block 0: edge_index -> Ahat as 18 pre-swizzled MFMA A-frags;
//              rest: weights (fragswizzled)
// gcn_fused:   src -> h2 = relu(Ahat@(relu(Ahat@X@W1+b1)@W2)+b2), ONE kernel,
//              ZERO barriers: wave w owns batch b0+w end-to-end; all
//              transposes are wave-private LDS round-trips (in-order DS);
//              Ahat A-frags straight from global (L2-hot); 38.9KB LDS ->
//              4 blocks/CU, 16 independent waves/CU.
// conv1/2/3:   pipelined hybrid GEMMs: A reg-prefetch + double-buffered LDS,
//              B direct-from-global fragswizzled (1 KB contiguous per wave)
// fc1_splitk:  c3 -> fp32 partials (6-way split-K, same pipeline)
// fc1_reduce:  partials -> feat (fp32 d_out) + fr (bf16 relu)
// cls1/cls2:   same template
// ---------------------------------------------------------------------------

typedef __attribute__((ext_vector_type(8))) short short8v;
typedef __attribute__((ext_vector_type(4))) float floatx4;

#define N_NODE 96
#define E_TOT  864
#define BATCH  8192ull

// ws layout, ushort elements
#define R0_OFF   0ull
#define R1_OFF   25165824ull
#define FR_OFF   50331648ull
#define R2_OFF   51380224ull
#define WT_OFF   52428800ull
#define W1N_OFF  (WT_OFF + 0)
#define W2N_OFF  (WT_OFF + 2048)
#define WC1_OFF  (WT_OFF + 4096)      // fragswizzled [4g][7ks][64][8]
#define WC2_OFF  (WT_OFF + 18432)     // [8g][10ks][64][8]
#define WC3_OFF  (WT_OFF + 59392)     // [16g][12ks][64][8]
#define WF1_OFF  (WT_OFF + 157696)    // [8g][96ks][64][8]
#define WL1_OFF  (WT_OFF + 550912)    // [8g][4ks][64][8]
#define WL2_OFF  (WT_OFF + 567296)    // [16g][4ks][64][8]
#define AH_OFF   (WT_OFF + 600064)    // Ahat as 18 A-frags [fm*3+kk][64][8]

__device__ __forceinline__ unsigned short f2b(float f) {
    unsigned int u = __builtin_bit_cast(unsigned int, f);
    u += 0x7fffu + ((u >> 16) & 1u);
    return (unsigned short)(u >> 16);
}
__device__ __forceinline__ float b2f(unsigned short h) {
    unsigned int u = ((unsigned int)h) << 16;
    return __builtin_bit_cast(float, u);
}

// ---------------------------------------------------------------------------
// Merged prep: block 0 builds Ahat A-frags from edges; blocks 1..2345 convert
// and fragswizzle all weights.
// ---------------------------------------------------------------------------
__global__ void prep_all(const int* __restrict__ eidx,
                         const float* __restrict__ g1w, const float* __restrict__ g2w,
                         const float* __restrict__ w1, const float* __restrict__ w2,
                         const float* __restrict__ w3, const float* __restrict__ f1,
                         const float* __restrict__ l1, const float* __restrict__ l2,
                         unsigned short* __restrict__ wt,
                         unsigned short* __restrict__ ahf) {
    __shared__ int rowv[E_TOT];
    __shared__ int colv[E_TOT];
    __shared__ int degi[N_NODE];
    __shared__ float dinv[N_NODE];
    __shared__ float ad[96 * 96];
    const int tid = threadIdx.x;
    if (blockIdx.x == 0) {
        for (int e = tid; e < E_TOT; e += 256) {
            int r, c;
            if (e < 768) { r = eidx[e]; c = eidx[768 + e]; }
            else         { r = e - 768; c = r; }
            rowv[e] = r; colv[e] = c;
        }
        for (int n = tid; n < N_NODE; n += 256) degi[n] = 0;
        for (int i = tid; i < 9216; i += 256) ad[i] = 0.f;
        __syncthreads();
        for (int e = tid; e < E_TOT; e += 256) atomicAdd(&degi[rowv[e]], 1);
        __syncthreads();
        for (int n = tid; n < N_NODE; n += 256)
            dinv[n] = rsqrtf(fmaxf((float)degi[n], 1e-12f));
        __syncthreads();
        for (int e = tid; e < E_TOT; e += 256)
            atomicAdd(&ad[rowv[e] * 96 + colv[e]], dinv[rowv[e]] * dinv[colv[e]]);
        __syncthreads();
        // write as 18 MFMA A-frags: frag f=fm*3+kk, lane ln, elem j ->
        // Ahat[fm*16 + (ln&15)][kk*32 + (ln>>4)*8 + j]
        for (int i = tid; i < 9216; i += 256) {
            int f = i >> 9, rm = i & 511;
            int ln = rm >> 3, j = rm & 7;
            int fm = f / 3, kk = f % 3;
            int row = fm * 16 + (ln & 15);
            int col = kk * 32 + (ln >> 4) * 8 + j;
            ahf[i] = f2b(ad[row * 96 + col]);
        }
        return;
    }
    // weights path: fragswizzled B layout — group g (16 n-cols), kstep ks
    // (32 k), lane = quad*16 + n16, j in [0,8): elem = B[g*16+n16][ks*32+quad*8+j]
    long idx = (long)(blockIdx.x - 1) * 256 + tid;
    if (idx >= 600064) return;
    float v;
    if (idx < 2048) {                      // w1n[o][c] (unswizzled; c>=16 ZERO)
        int o = idx >> 5, c = idx & 31;
        v = (c < 16) ? g1w[c * 64 + o] : 0.f;
    } else if (idx < 4096) {               // w2n[g][c] (unswizzled)
        long j = idx - 2048; int g = j >> 6, c = j & 63;
        v = g2w[c * 32 + g];
    } else {
        long base, KS;
        int region;
        if      (idx < 18432)  { base = 4096;   KS = 7;  region = 0; }
        else if (idx < 59392)  { base = 18432;  KS = 10; region = 1; }
        else if (idx < 157696) { base = 59392;  KS = 12; region = 2; }
        else if (idx < 550912) { base = 157696; KS = 96; region = 3; }
        else if (idx < 567296) { base = 550912; KS = 4;  region = 4; }
        else                   { base = 567296; KS = 4;  region = 5; }
        long local = idx - base;
        long g  = local / (KS * 512);
        long rm = local % (KS * 512);
        long ks = rm / 512;
        int lane = (int)((rm % 512) / 8);
        int j    = (int)(rm % 8);
        int quad = lane >> 4, n16 = lane & 15;
        int n = (int)(g * 16 + n16);
        int k = (int)(ks * 32 + quad * 8 + j);
        switch (region) {
            case 0: { int t = k / 32,  c = k % 32;  v = w1[n * 224 + c * 7 + t]; } break;
            case 1: { int t = k / 64,  c = k % 64;  v = w2[n * 320 + c * 5 + t]; } break;
            case 2: { int t = k / 128, c = k % 128; v = w3[n * 384 + c * 3 + t]; } break;
            case 3: { int t = k / 256, o = k % 256; v = f1[(o * 12 + t) * 128 + n]; } break;
            case 4: v = l1[k * 128 + n]; break;
            default: v = (n < 210) ? l2[k * 210 + n] : 0.f; break;
        }
    }
    wt[idx] = f2b(v);
}

// ---------------------------------------------------------------------------
// Fused GCN front-end, barrier-free. Wave w of block b owns batch bb=b*4+w.
// Per-wave LDS (4864 ush): [XAc 16x24 | H1W 16x72 | HWT 32x104]; the final
// C-staging [96][32] overlays the same region (in-order same-wave DS makes
// write-after-read safe). Ahat A-frags + W1/W2 B-frags read from global.
// All transposes (MFMA C-layout -> A/B-frag layout) are wave-private LDS
// round-trips; XA upper-k reads are garbage x zero-W1-rows (exact).
// ---------------------------------------------------------------------------
__launch_bounds__(256, 4)
__global__ void gcn_fused(const float* __restrict__ src,
                          const unsigned short* __restrict__ ahf,
                          const unsigned short* __restrict__ w1n,
                          const unsigned short* __restrict__ w2n,
                          const float* __restrict__ b1,
                          const float* __restrict__ b2,
                          unsigned short* __restrict__ h2) {
    __shared__ __align__(16) unsigned short pool[4 * 4864];
    const int tid = threadIdx.x;
    const int w = tid >> 6, lane = tid & 63, quad = lane >> 4, m16 = lane & 15;
    unsigned short* P   = pool + w * 4864;
    unsigned short* XAc = P;           // [16][24] (+garbage guard into H1W)
    unsigned short* H1W = P + 384;     // [16][72]
    unsigned short* HWT = P + 1536;    // [32][104]  hw2^T [ch][node]
    unsigned short* Cw  = P;           // [96][32] epilogue overlay
    const size_t bb = (size_t)blockIdx.x * 4 + w;

    // weight B-frags + biases (global, L2-hot)
    short8v w1f[4], w2f[2][2];
    float bv1[4], bv2[2];
#pragma unroll
    for (int fn = 0; fn < 4; fn++) {
        w1f[fn] = *(const short8v*)&w1n[(fn * 16 + m16) * 32 + quad * 8];
        bv1[fn] = b1[fn * 16 + m16];
    }
#pragma unroll
    for (int fn = 0; fn < 2; fn++) {
#pragma unroll
        for (int kk = 0; kk < 2; kk++)
            w2f[fn][kk] = *(const short8v*)&w2n[(fn * 16 + m16) * 64 + kk * 32 + quad * 8];
        bv2[fn] = b2[fn * 16 + m16];
    }

    // S2: XA = Ahat @ X. B-frag = 8 consecutive floats of src[bb][c=m16][k0..],
    // gathered per-lane (each src byte read exactly once per wave).
    floatx4 acc[6] = {};
    const float* sB = src + bb * 1536 + (size_t)m16 * 96;
#pragma unroll
    for (int kk = 0; kk < 3; kk++) {
        float4 f0 = *(const float4*)&sB[kk * 32 + quad * 8];
        float4 f1 = *(const float4*)&sB[kk * 32 + quad * 8 + 4];
        short8v bfr;
        bfr[0] = (short)f2b(f0.x); bfr[1] = (short)f2b(f0.y);
        bfr[2] = (short)f2b(f0.z); bfr[3] = (short)f2b(f0.w);
        bfr[4] = (short)f2b(f1.x); bfr[5] = (short)f2b(f1.y);
        bfr[6] = (short)f2b(f1.z); bfr[7] = (short)f2b(f1.w);
#pragma unroll
        for (int fm = 0; fm < 6; fm++) {
            short8v afr = *(const short8v*)&ahf[((fm * 3 + kk) << 9) + lane * 8];
            acc[fm] = __builtin_amdgcn_mfma_f32_16x16x32_bf16(afr, bfr, acc[fm], 0, 0, 0);
        }
    }

    // S3/S4: per 16-node chunk: XA -> (XA@W1 relu) -> (@W2) -> HWT, all
    // wave-private round-trips.
#pragma unroll
    for (int cc = 0; cc < 6; cc++) {
#pragma unroll
        for (int r = 0; r < 4; r++)
            XAc[(quad * 4 + r) * 24 + m16] = f2b(acc[cc][r]);
        short8v afr1 = *(const short8v*)&XAc[m16 * 24 + quad * 8];
        floatx4 a1[4];
#pragma unroll
        for (int fn = 0; fn < 4; fn++) {
            floatx4 zc = {0.f, 0.f, 0.f, 0.f};
            a1[fn] = __builtin_amdgcn_mfma_f32_16x16x32_bf16(afr1, w1f[fn], zc, 0, 0, 0);
        }
#pragma unroll
        for (int fn = 0; fn < 4; fn++)
#pragma unroll
            for (int r = 0; r < 4; r++)
                H1W[(quad * 4 + r) * 72 + fn * 16 + m16] =
                    f2b(fmaxf(a1[fn][r] + bv1[fn], 0.f));
        floatx4 a2[2] = {};
#pragma unroll
        for (int kk = 0; kk < 2; kk++) {
            short8v afr2 = *(const short8v*)&H1W[m16 * 72 + kk * 32 + quad * 8];
#pragma unroll
            for (int fn = 0; fn < 2; fn++)
                a2[fn] = __builtin_amdgcn_mfma_f32_16x16x32_bf16(afr2, w2f[fn][kk], a2[fn], 0, 0, 0);
        }
#pragma unroll
        for (int fn = 0; fn < 2; fn++)
#pragma unroll
            for (int r = 0; r < 4; r++)
                HWT[(fn * 16 + m16) * 104 + cc * 16 + quad * 4 + r] = f2b(a2[fn][r]);
    }

    // S5: h2 = relu(Ahat @ hw2 + b2) for batch bb.
    floatx4 c2a[6][2] = {};
#pragma unroll
    for (int kk = 0; kk < 3; kk++) {
        short8v bfr[2];
#pragma unroll
        for (int fn = 0; fn < 2; fn++)
            bfr[fn] = *(const short8v*)&HWT[(fn * 16 + m16) * 104 + kk * 32 + quad * 8];
#pragma unroll
        for (int fm = 0; fm < 6; fm++) {
            short8v afr = *(const short8v*)&ahf[((fm * 3 + kk) << 9) + lane * 8];
#pragma unroll
            for (int fn = 0; fn < 2; fn++)
                c2a[fm][fn] = __builtin_amdgcn_mfma_f32_16x16x32_bf16(afr, bfr[fn], c2a[fm][fn], 0, 0, 0);
        }
    }
    // epilogue: bias+relu+f2b -> Cw overlay, then coalesced 16B stores
#pragma unroll
    for (int fm = 0; fm < 6; fm++)
#pragma unroll
        for (int fn = 0; fn < 2; fn++)
#pragma unroll
            for (int r = 0; r < 4; r++)
                Cw[(fm * 16 + quad * 4 + r) * 32 + fn * 16 + m16] =
                    f2b(fmaxf(c2a[fm][fn][r] + bv2[fn], 0.f));
#pragma unroll
    for (int it = 0; it < 6; it++) {
        int idx = it * 64 + lane;          // 16B chunk id, 384 total
        int node = idx >> 2, q8 = idx & 3;
        *(uint4*)&h2[((size_t)node * BATCH + bb) * 32 + q8 * 8] =
            *(const uint4*)&Cw[idx * 8];
    }
}

// ---------------------------------------------------------------------------
// Pipelined hybrid slab GEMM: per stage, barrier -> issue next A-tile global
// loads (regs) -> MFMA on LDS buf[p] (hides load latency) -> write regs ->
// buf[p^1]. One barrier/stage; out-of-range taps zero-fill (exact).
// B direct-from-global fragswizzled. BM=WM*32, BN=FN*32, waves 2x2.
// MODE 0: bf16 out + bias + relu. MODE 4: fp32 out [210-stride], masked.
// ---------------------------------------------------------------------------
template<int WM, int FN, int NTAP, int CIN, int NOUT, int STRIDE, int PAD, int LIN, int BK, int MODE>
__launch_bounds__(256)
__global__ void gemm_slab(const unsigned short* __restrict__ in,
                          const unsigned short* __restrict__ wn,
                          const float* __restrict__ bias,
                          unsigned short* __restrict__ outb,
                          float* __restrict__ outf) {
    constexpr int BM  = WM * 32;
    constexpr int BN  = FN * 32;
    constexpr int BKP = BK + 8;
    constexpr int CPT = CIN / BK;
    constexpr int NC  = NTAP * CPT;
    constexpr int KS  = NTAP * CIN / 32;     // fragswizzle ksteps
    constexpr int NV  = BM * BK / 8 / 256;   // vec8 loads per thread per tile
    constexpr int RPV = 256 / (BK / 8);      // rows per 256-thread sweep
    constexpr int SZ1 = 2 * BM * BKP;
    constexpr int SZ2 = (MODE == 4) ? 16 : BM * (BN + 8);
    constexpr int POOL = SZ1 > SZ2 ? SZ1 : SZ2;
    __shared__ __align__(16) unsigned short pool[POOL];
    const int tid = threadIdx.x;
    const size_t b0 = blockIdx.x * BM;
    const int n0 = blockIdx.y * BN;
    const int l  = blockIdx.z;
    const int w = tid >> 6, lane = tid & 63, quad = lane >> 4, m16 = lane & 15;
    const int wm = w >> 1, wq = w & 1;
    const int mbase = wm * (WM * 16), nbase = wq * (FN * 16);
    const int gw = (n0 + nbase) >> 4;        // first 16-col weight group
    const int lr = tid / (BK / 8);           // staging row
    const int lc = tid % (BK / 8);           // staging vec8 col
    floatx4 acc[WM][FN] = {};
    const short8v zz8 = {0, 0, 0, 0, 0, 0, 0, 0};

    short8v pre[NV], nxt[NV];
    // prologue: load + write tile 0
    {
        int pos = STRIDE * l - PAD;
        if (pos >= 0 && pos < LIN) {
            const unsigned short* ag = in + ((size_t)pos * BATCH + b0) * CIN;
#pragma unroll
            for (int v = 0; v < NV; v++)
                pre[v] = *(const short8v*)&ag[(size_t)(lr + v * RPV) * CIN + lc * 8];
        } else {
#pragma unroll
            for (int v = 0; v < NV; v++) pre[v] = zz8;
        }
#pragma unroll
        for (int v = 0; v < NV; v++)
            *(short8v*)&pool[(lr + v * RPV) * BKP + lc * 8] = pre[v];
    }
    int p = 0;
#pragma unroll
    for (int ch = 0; ch < NC; ++ch) {
        __syncthreads();                      // buf[p] ready; no VMEM in flight
        if (ch + 1 < NC) {                    // issue next tile's global loads
            int t = (ch + 1) / CPT, inner = (ch + 1) % CPT;
            int pos = STRIDE * l + t - PAD;
            if (pos >= 0 && pos < LIN) {
                const unsigned short* ag = in + ((size_t)pos * BATCH + b0) * CIN + inner * BK;
#pragma unroll
                for (int v = 0; v < NV; v++)
                    nxt[v] = *(const short8v*)&ag[(size_t)(lr + v * RPV) * CIN + lc * 8];
            } else {
#pragma unroll
                for (int v = 0; v < NV; v++) nxt[v] = zz8;
            }
        }
        // MFMA on buf[p] — overlaps with the loads above
        const unsigned short* As = pool + p * BM * BKP;
        const int kbase = (ch / CPT) * CIN + (ch % CPT) * BK;
#pragma unroll
        for (int kk = 0; kk < BK; kk += 32) {
            const int ksG = (kbase + kk) >> 5;
            short8v bfr[FN];
#pragma unroll
            for (int fn = 0; fn < FN; fn++)
                bfr[fn] = *(const short8v*)&wn[(((size_t)(gw + fn) * KS + ksG) << 9) + lane * 8];
#pragma unroll
            for (int fm = 0; fm < WM; fm++) {
                short8v afr = *(const short8v*)&As[(mbase + fm * 16 + m16) * BKP + kk + quad * 8];
#pragma unroll
                for (int fn = 0; fn < FN; fn++)
                    acc[fm][fn] = __builtin_amdgcn_mfma_f32_16x16x32_bf16(afr, bfr[fn], acc[fm][fn], 0, 0, 0);
            }
        }
        if (ch + 1 < NC) {                    // write next into other buffer
            unsigned short* Ad = pool + (p ^ 1) * BM * BKP;
#pragma unroll
            for (int v = 0; v < NV; v++)
                *(short8v*)&Ad[(lr + v * RPV) * BKP + lc * 8] = nxt[v];
        }
        p ^= 1;
    }

    if constexpr (MODE == 4) {
#pragma unroll
        for (int fn = 0; fn < FN; fn++) {
            int cg = n0 + nbase + fn * 16 + m16;
            float bv = (cg < 210) ? bias[cg] : 0.f;
            if (cg < 210) {
#pragma unroll
                for (int fm = 0; fm < WM; fm++)
#pragma unroll
                    for (int r = 0; r < 4; r++) {
                        size_t row = b0 + mbase + fm * 16 + quad * 4 + r;
                        outf[row * 210 + cg] = acc[fm][fn][r] + bv;
                    }
            }
        }
    } else {
        float bv[FN];
#pragma unroll
        for (int fn = 0; fn < FN; fn++) bv[fn] = bias[n0 + nbase + fn * 16 + m16];
        __syncthreads();                      // all MFMA reads of pool done
        unsigned short* Cs = pool;
#pragma unroll
        for (int fm = 0; fm < WM; fm++)
#pragma unroll
            for (int r = 0; r < 4; r++) {
                int row = mbase + fm * 16 + quad * 4 + r;
#pragma unroll
                for (int fn = 0; fn < FN; fn++)
                    Cs[row * (BN + 8) + nbase + fn * 16 + m16] =
                        f2b(fmaxf(acc[fm][fn][r] + bv[fn], 0.f));
            }
        __syncthreads();
        for (int u = tid; u < BM * (BN / 8); u += 256) {
            int r = u / (BN / 8), cc = u % (BN / 8);
            *(short8v*)&outb[((size_t)l * BATCH + b0 + r) * NOUT + n0 + cc * 8] =
                *(short8v*)&Cs[r * (BN + 8) + cc * 8];
        }
    }
}

// ---------------------------------------------------------------------------
// fc1 split-K, pipelined: A (c3) reg-prefetch + dbuf LDS; B fragswizzled.
// grid (64, 1, 6); z handles taps {2z, 2z+1} (K=512, 8 stages of 64).
// ---------------------------------------------------------------------------
__launch_bounds__(256)
__global__ void fc1_splitk(const unsigned short* __restrict__ c3,
                           const unsigned short* __restrict__ wf1,
                           float* __restrict__ part) {
    __shared__ __align__(16) unsigned short pool[2 * 128 * 72];
    const int tid = threadIdx.x;
    const size_t b0 = blockIdx.x * 128;
    const int kg = blockIdx.z;
    const int w = tid >> 6, lane = tid & 63, quad = lane >> 4, m16 = lane & 15;
    const int wm = w >> 1, wq = w & 1;
    const int mbase = wm * 64, nbase = wq * 64;
    const int gw = nbase >> 4;
    const int lr = tid >> 3, lc = tid & 7;
    floatx4 acc[4][4] = {};
    short8v pre[4], nxt[4];

    // stage s: t = kg*2 + (s>>2), inner = s&3
    {
        const unsigned short* ag = c3 + ((size_t)(kg * 2) * BATCH + b0) * 256;
#pragma unroll
        for (int v = 0; v < 4; v++)
            pre[v] = *(const short8v*)&ag[(size_t)(lr + v * 32) * 256 + lc * 8];
#pragma unroll
        for (int v = 0; v < 4; v++)
            *(short8v*)&pool[(lr + v * 32) * 72 + lc * 8] = pre[v];
    }
    int p = 0;
#pragma unroll
    for (int s = 0; s < 8; ++s) {
        __syncthreads();
        if (s + 1 < 8) {
            int t = kg * 2 + ((s + 1) >> 2), inner = (s + 1) & 3;
            const unsigned short* ag = c3 + ((size_t)t * BATCH + b0) * 256 + inner * 64;
#pragma unroll
            for (int v = 0; v < 4; v++)
                nxt[v] = *(const short8v*)&ag[(size_t)(lr + v * 32) * 256 + lc * 8];
        }
        const unsigned short* As = pool + p * 128 * 72;
        const int kbase = (kg * 2 + (s >> 2)) * 256 + (s & 3) * 64;
#pragma unroll
        for (int kk = 0; kk < 64; kk += 32) {
            const int ksG = (kbase + kk) >> 5;    // KS = 96
            short8v bfr[4];
#pragma unroll
            for (int fn = 0; fn < 4; fn++)
                bfr[fn] = *(const short8v*)&wf1[(((size_t)(gw + fn) * 96 + ksG) << 9) + lane * 8];
#pragma unroll
            for (int fm = 0; fm < 4; fm++) {
                short8v afr = *(const short8v*)&As[(mbase + fm * 16 + m16) * 72 + kk + quad * 8];
#pragma unroll
                for (int fn = 0; fn < 4; fn++)
                    acc[fm][fn] = __builtin_amdgcn_mfma_f32_16x16x32_bf16(afr, bfr[fn], acc[fm][fn], 0, 0, 0);
            }
        }
        if (s + 1 < 8) {
            unsigned short* Ad = pool + (p ^ 1) * 128 * 72;
#pragma unroll
            for (int v = 0; v < 4; v++)
                *(short8v*)&Ad[(lr + v * 32) * 72 + lc * 8] = nxt[v];
        }
        p ^= 1;
    }
    float* pg = part + (size_t)kg * BATCH * 128;
#pragma unroll
    for (int fm = 0; fm < 4; fm++)
#pragma unroll
        for (int r = 0; r < 4; r++) {
            size_t row = b0 + mbase + fm * 16 + quad * 4 + r;
#pragma unroll
            for (int fn = 0; fn < 4; fn++)
                pg[row * 128 + nbase + fn * 16 + m16] = acc[fm][fn][r];
        }
}

// ---------------------------------------------------------------------------
__launch_bounds__(256)
__global__ void fc1_reduce(const float* __restrict__ part, const float* __restrict__ bias,
                           float* __restrict__ feat, unsigned short* __restrict__ fr) {
    const size_t idx = (size_t)blockIdx.x * 256 + threadIdx.x;
    const size_t row = idx >> 5;
    const int    c4  = (int)(idx & 31);
    float4 s = *(const float4*)&bias[c4 * 4];
#pragma unroll
    for (int z = 0; z < 6; z++) {
        float4 p = *(const float4*)&part[(z * BATCH + row) * 128 + c4 * 4];
        s.x += p.x; s.y += p.y; s.z += p.z; s.w += p.w;
    }
    *(float4*)&feat[row * 128 + c4 * 4] = s;
    unsigned int d0 = (unsigned int)f2b(fmaxf(s.x, 0.f)) |
                      ((unsigned int)f2b(fmaxf(s.y, 0.f)) << 16);
    unsigned int d1 = (unsigned int)f2b(fmaxf(s.z, 0.f)) |
                      ((unsigned int)f2b(fmaxf(s.w, 0.f)) << 16);
    *(uint2*)&fr[row * 128 + c4 * 4] = make_uint2(d0, d1);
}

// ---------------------------------------------------------------------------
extern "C" void kernel_launch(void* const* d_in, const int* in_sizes, int n_in,
                              void* d_out, int out_size, void* d_ws, size_t ws_size,
                              hipStream_t stream) {
    const float* src  = (const float*)d_in[0];
    const int*   eidx = (const int*)  d_in[1];
    const float* g1w  = (const float*)d_in[2];
    const float* g1b  = (const float*)d_in[3];
    const float* g2w  = (const float*)d_in[4];
    const float* g2b  = (const float*)d_in[5];
    const float* cv1w = (const float*)d_in[6];
    const float* cv1b = (const float*)d_in[7];
    const float* cv2w = (const float*)d_in[8];
    const float* cv2b = (const float*)d_in[9];
    const float* cv3w = (const float*)d_in[10];
    const float* cv3b = (const float*)d_in[11];
    const float* fc1w = (const float*)d_in[12];
    const float* fc1b = (const float*)d_in[13];
    const float* cl1w = (const float*)d_in[14];
    const float* cl1b = (const float*)d_in[15];
    const float* cl2w = (const float*)d_in[16];
    const float* cl2b = (const float*)d_in[17];

    unsigned short* ws16 = (unsigned short*)d_ws;
    float* wsF = (float*)d_ws;
    float* out = (float*)d_out;

    unsigned short* h2  = ws16 + R0_OFF;
    unsigned short* c1  = ws16 + R1_OFF;
    unsigned short* c2  = ws16 + R0_OFF;
    unsigned short* c3  = ws16 + R1_OFF;
    float*          part = wsF;              // aliases dead c2 (R0)
    unsigned short* fr  = ws16 + FR_OFF;
    unsigned short* r2  = ws16 + R2_OFF;
    unsigned short* w1n = ws16 + W1N_OFF;
    unsigned short* w2n = ws16 + W2N_OFF;
    unsigned short* wc1 = ws16 + WC1_OFF;
    unsigned short* wc2 = ws16 + WC2_OFF;
    unsigned short* wc3 = ws16 + WC3_OFF;
    unsigned short* wf1 = ws16 + WF1_OFF;
    unsigned short* wl1 = ws16 + WL1_OFF;
    unsigned short* wl2 = ws16 + WL2_OFF;
    unsigned short* ahf = ws16 + AH_OFF;

    float* feat_out = out + 8192ull * 210ull;

    prep_all<<<2346, 256, 0, stream>>>(eidx, g1w, g2w, cv1w, cv2w, cv3w, fc1w, cl1w, cl2w,
                                       ws16 + WT_OFF, ahf);
    gcn_fused<<<2048, 256, 0, stream>>>(src, ahf, w1n, w2n, g1b, g2b, h2);
    // conv1: BM=256, BN=64, BK=32, 7 pipelined stages
    gemm_slab<8, 2, 7, 32, 64, 2, 3, 96, 32, 0>
        <<<dim3(32, 1, 48), 256, 0, stream>>>(h2, wc1, cv1b, c1, nullptr);
    // conv2: BM=128, BN=128, BK=64, 10 stages
    gemm_slab<4, 4, 5, 64, 128, 2, 2, 48, 64, 0>
        <<<dim3(64, 1, 24), 256, 0, stream>>>(c1, wc2, cv2b, c2, nullptr);
    // conv3: BM=128, BN=128 (y=2), BK=64, 6 stages
    gemm_slab<4, 4, 3, 128, 256, 2, 1, 24, 64, 0>
        <<<dim3(64, 2, 12), 256, 0, stream>>>(c2, wc3, cv3b, c3, nullptr);
    fc1_splitk<<<dim3(64, 1, 6), 256, 0, stream>>>(c3, wf1, part);
    fc1_reduce<<<1024, 256, 0, stream>>>(part, fc1b, feat_out, fr);
    gemm_slab<2, 2, 1, 128, 128, 1, 0, 1, 64, 0>
        <<<dim3(128, 2, 1), 256, 0, stream>>>(fr, wl1, cl1b, r2, nullptr);
    gemm_slab<2, 2, 1, 128, 256, 1, 0, 1, 64, 4>
        <<<dim3(128, 4, 1), 256, 0, stream>>>(r2, wl2, cl2b, nullptr, out);
}